// Round 9
// baseline (776.284 us; speedup 1.0000x reference)
//
#include <hip/hip_runtime.h>
#include <math.h>

#define TSTEPS 12
#define BATCH  2048
#define IMG    512
#define HIDN   1024
#define NCLASS 51
#define SCALE_X 1.7320508075688772f      // sqrt(1 + 2*e^0) = sqrt(3)

typedef __attribute__((ext_vector_type(8)))  _Float16 f16x8;
typedef __attribute__((ext_vector_type(2)))  _Float16 f16x2;
typedef __attribute__((ext_vector_type(16))) float    f32x16;

__device__ __forceinline__ float sigf(float x) {
    return 1.f / (1.f + __expf(-x));
}

// s_waitcnt imm: vmcnt(n), lgkmcnt=15 (no wait), expcnt=7 (no wait)
#define VMCNT_IMM(n) (0x0F70 | (n))

// ===========================================================================
// Fragment-ordered layout (as R8): matrix [R x K] fp16 stored as 1KB chunks
// over (rt=row/32, kt=k/16); chunk idx = rt*(K/16)+kt; lane l owns halfs
// [l*8, l*8+8) = (row = rt*32+(l&31), k = kt*16+(l>>5)*8+j). Matches the
// v_mfma_f32_32x32x16_f16 A/B fragment; ds_read_b128 lane-stride 16B.
// ===========================================================================

// ---------------------------------------------------------------------------
// Fused fp16 MFMA GEMM + SRU recurrence. 32x32x16 MFMA.
// K-loop: 3-buffer ring, raw s_barrier + per-wave s_waitcnt vmcnt(NS):
//   iter i: [vmcnt(NS) -> own stage(i) landed; s_barrier -> everyone's
//   stage(i) landed & compute(i-1) done; issue stage(i+2) into buf (i+2)%3
//   (readers done at i-1); compute(i)]. stage(i+1) stays in flight across
//   the barrier -- no vmcnt(0) drain (the m97 stall).
// ---------------------------------------------------------------------------
template<int TJ, int NCOMP>
__global__ __launch_bounds__(256, 2)
void gemm_sru(const _Float16* __restrict__ A, const _Float16* __restrict__ Bt,
              const _Float16* __restrict__ resid,
              const float* __restrict__ vc, const float* __restrict__ bias,
              _Float16* __restrict__ hout, float* __restrict__ hbar, int K,
              int pcshift) {
    constexpr int BN    = 64 * TJ;
    constexpr int NCH   = BN / NCOMP;
    constexpr int ATILE = 192 * 32;            // halfs per A buffer (12 KB)
    constexpr int BTILE = BN * 32;
    constexpr int S_A3  = 3 * ATILE;
    constexpr int EPAD  = BN + 8;
    constexpr int EPI   = 96 * EPAD;
    constexpr int HREG  = 96 * NCH;
    constexpr int KTH   = NCH / 16;
    constexpr int PAIRS = NCH / 2;
    constexpr int STG   = 3 * (ATILE + BTILE);
    constexpr int TOT   = STG > (EPI + HREG) ? STG : (EPI + HREG);
    __shared__ __align__(16) _Float16 smem[TOT];

    const int tid  = threadIdx.x;
    const int lane = tid & 63;
    const int w    = tid >> 6;

    // ---- XCD swizzle: columns ≡ xk (mod 8) stay on one XCD (W-stationary) --
    const int nbx = gridDim.x;
    const int b   = blockIdx.y * nbx + blockIdx.x;
    const int pc1 = (nbx >> 3) - 1;            // pc = nbx/8 (pow2)
    const int xk  = b & 7, s = b >> 3;
    const int bx  = xk + ((s & pc1) << 3);
    const int by  = s >> pcshift;

    const int bm  = by * 192;
    const int KT  = K >> 4;

    // ---- staging assignment (wave-uniform) ---------------------------------
    const bool isA = (w < 2);
    const int  nst = isA ? 3 : TJ;             // 32-row chunks per wave
    const _Float16* gsrc = isA ? A : Bt;
    const int rt0g = (isA ? (bm >> 5) : (bx * (BN >> 5))) + (w & 1) * nst;
    const _Float16* gbase = gsrc + (size_t)rt0g * KT * 512 + (lane << 3);
    const int lds0  = isA ? 0 : S_A3;
    const int ltile = isA ? ATILE : BTILE;
    const int lhalf = (w & 1) * nst * 1024;

    auto stage = [&](int buf, int k0) {
        const _Float16* g = gbase + (size_t)(k0 >> 4) * 512;
        _Float16* l = smem + lds0 + buf * ltile + lhalf;
        for (int i = 0; i < nst; ++i)
            #pragma unroll
            for (int kt = 0; kt < 2; ++kt)
                __builtin_amdgcn_global_load_lds(
                    (const __attribute__((address_space(1))) unsigned int*)(g + ((size_t)i * KT + kt) * 512),
                    (__attribute__((address_space(3))) unsigned int*)(l + (i * 2 + kt) * 512),
                    16, 0, 0);
    };

    const int wy32 = (w >> 1) * 3;
    const int wx32 = (w & 1) * TJ;
    const int l5   = lane >> 5;
    const int m32  = lane & 31;

    f32x16 acc[3][TJ];
    #pragma unroll
    for (int i = 0; i < 3; ++i)
        #pragma unroll
        for (int j = 0; j < TJ; ++j)
            #pragma unroll
            for (int r = 0; r < 16; ++r) acc[i][j][r] = 0.f;

    stage(0, 0);
    stage(1, 32);                              // K >= 64 always here
    int bi = 0;
    for (int k0 = 0; k0 < K; k0 += 32) {
        // wait own stage(k0); keep stage(k0+32) (NS loads) in flight
        if (k0 + 32 < K) {
            if (isA) __builtin_amdgcn_s_waitcnt(VMCNT_IMM(6));
            else     __builtin_amdgcn_s_waitcnt(VMCNT_IMM(2 * TJ));
        } else {
            __builtin_amdgcn_s_waitcnt(VMCNT_IMM(0));
        }
        __builtin_amdgcn_s_barrier();
        if (k0 + 64 < K) {
            int nb = bi + 2; if (nb >= 3) nb -= 3;
            stage(nb, k0 + 64);
        }

        const _Float16* la = smem + bi * ATILE;
        const _Float16* lb = smem + S_A3 + bi * BTILE;
        #pragma unroll
        for (int ks = 0; ks < 2; ++ks) {
            f16x8 a[3], bfr[TJ];
            #pragma unroll
            for (int i = 0; i < 3; ++i)
                a[i] = *(const f16x8*)&la[((wy32 + i) * 2 + ks) * 512 + (lane << 3)];
            #pragma unroll
            for (int j = 0; j < TJ; ++j)
                bfr[j] = *(const f16x8*)&lb[((wx32 + j) * 2 + ks) * 512 + (lane << 3)];
            #pragma unroll
            for (int i = 0; i < 3; ++i)
                #pragma unroll
                for (int j = 0; j < TJ; ++j)
                    acc[i][j] = __builtin_amdgcn_mfma_f32_32x32x16_f16(
                        a[i], bfr[j], acc[i][j], 0, 0, 0);
        }
        ++bi; if (bi == 3) bi = 0;
    }

    // ---- epilogue: two passes of 96 rows (8 whole batches each) ------------
    _Float16 (*uld)[EPAD] = (_Float16 (*)[EPAD])smem;
    _Float16* hreg = smem + EPI;
    const int bl   = tid / PAIRS;
    const int pr   = tid % PAIRS;
    const int gcol = bx * NCH + pr * 2;

    #pragma unroll
    for (int pass = 0; pass < 2; ++pass) {
        __syncthreads();
        if ((w >> 1) == pass) {
            #pragma unroll
            for (int i = 0; i < 3; ++i)
                #pragma unroll
                for (int j = 0; j < TJ; ++j)
                    #pragma unroll
                    for (int r = 0; r < 16; ++r) {
                        const int row = i * 32 + (r & 3) + 8 * (r >> 2) + 4 * l5;
                        uld[row][(wx32 + j) * 32 + m32] = (_Float16)acc[i][j][r];
                    }
        }
        __syncthreads();

        if (tid < 8 * PAIRS) {
            const float2 vf  = *(const float2*)&vc[gcol];
            const float2 vr  = *(const float2*)&vc[HIDN + gcol];
            const float2 bfv = *(const float2*)&bias[gcol];
            const float2 brv = *(const float2*)&bias[HIDN + gcol];
            const int ca = (pr * 2) * NCOMP, cb = (pr * 2 + 1) * NCOMP;

            float c0 = 0.f, c1 = 0.f, s0 = 0.f, s1 = 0.f;
            #pragma unroll
            for (int t = 0; t < TSTEPS; ++t) {
                const int row = bl * 12 + t;
                const float u0a = (float)uld[row][ca + 0];
                const float u1a = (float)uld[row][ca + 1];
                const float u2a = (float)uld[row][ca + 2];
                const float u0b = (float)uld[row][cb + 0];
                const float u1b = (float)uld[row][cb + 1];
                const float u2b = (float)uld[row][cb + 2];
                float xta, xtb;
                if (NCOMP == 4) {
                    xta = (float)uld[row][ca + 3];
                    xtb = (float)uld[row][cb + 3];
                } else {
                    const int grow = bm + pass * 96 + row;
                    const size_t gran = ((size_t)(grow >> 5) * KT + (gcol >> 4)) * 512
                                      + (size_t)((grow & 31) + ((gcol >> 3) & 1) * 32) * 8
                                      + (gcol & 7);
                    const f16x2 xv = *(const f16x2*)&resid[gran];
                    xta = (float)xv[0]; xtb = (float)xv[1];
                }

                const float f0 = sigf(u1a + vf.x * c0 + bfv.x);
                c0 = f0 * c0 + (1.f - f0) * u0a;
                const float r0_ = sigf(u2a + vr.x * c0 + brv.x);
                const float th0 = 2.f * sigf(2.f * c0) - 1.f;
                const float hv0 = r0_ * th0 + (1.f - r0_) * xta * SCALE_X;

                const float f1 = sigf(u1b + vf.y * c1 + bfv.y);
                c1 = f1 * c1 + (1.f - f1) * u0b;
                const float r1_ = sigf(u2b + vr.y * c1 + brv.y);
                const float th1 = 2.f * sigf(2.f * c1) - 1.f;
                const float hv1 = r1_ * th1 + (1.f - r1_) * xtb * SCALE_X;

                if (hout) {
                    const int rtl  = row >> 5;
                    const int ktl  = pr >> 3;
                    const int lloc = (row & 31) + ((pr >> 2) & 1) * 32;
                    f16x2 hv = { (_Float16)hv0, (_Float16)hv1 };
                    *(f16x2*)&hreg[(rtl * KTH + ktl) * 512 + lloc * 8 + (pr & 3) * 2] = hv;
                }
                s0 += hv0; s1 += hv1;
            }
            if (hbar) {
                const int gb = bm / 12 + pass * 8 + bl;
                *(float2*)&hbar[(size_t)gb * HIDN + gcol] =
                    make_float2(s0 * (1.f / TSTEPS), s1 * (1.f / TSTEPS));
            }
        }

        if (hout) {
            __syncthreads();
            const int rtg0 = (bm + pass * 96) >> 5;
            for (int g = tid; g < HREG / 8; g += 256) {
                const int c = g >> 6, l = g & 63;
                const f16x8 v = *(const f16x8*)&hreg[c * 512 + l * 8];
                const int rtl = c / KTH, ktl = c % KTH;
                const size_t gc = (size_t)(rtg0 + rtl) * 64 + bx * KTH + ktl;
                *(f16x8*)&hout[gc * 512 + l * 8] = v;
            }
        }
    }
}

// ---------------------------------------------------------------------------
// Weight prep (coalesced, LDS transpose): W (K x N fp32, col n = comp*1024+h)
// -> fragment-ordered fp16 plane, row n' = h*NC + comp.
// Block = (rt, kc): 32 plane-rows x 128 k. Reads near-coalesced (n runs),
// writes 16B/lane coalesced chunks.
// ---------------------------------------------------------------------------
template<int NC>
__global__ __launch_bounds__(256)
void wsplit_t(const float* __restrict__ W, _Float16* __restrict__ Wt, int K) {
    __shared__ _Float16 tile[32][132];
    const int N  = NC * 1024;
    const int KT = K >> 4;
    const int rt = blockIdx.x, kc = blockIdx.y;

    const int nl = threadIdx.x & 31;           // plane-row local
    const int kl = threadIdx.x >> 5;           // 0..7
    const int np = rt * 32 + nl;
    const int h  = np / NC, comp = np - h * NC;
    const int n  = comp * 1024 + h;
    #pragma unroll
    for (int kk = 0; kk < 16; ++kk) {
        const int k = kc * 128 + kl * 16 + kk;
        tile[nl][kl * 16 + kk] = (_Float16)W[(size_t)k * N + n];
    }
    __syncthreads();

    #pragma unroll
    for (int p = 0; p < 2; ++p) {
        const int slot = p * 256 + threadIdx.x;
        const int ktl  = slot >> 6, l = slot & 63;
        f16x8 v;
        #pragma unroll
        for (int j = 0; j < 8; ++j)
            v[j] = tile[l & 31][ktl * 16 + ((l >> 5) << 3) + j];
        const int kt = kc * 8 + ktl;
        *(f16x8*)&Wt[((size_t)rt * KT + kt) * 512 + l * 8] = v;
    }
}

// ---------------------------------------------------------------------------
// x (rows x 512 fp32 row-major) -> fragment-ordered fp16. Block = (rt, kc):
// 32 rows x 128 k. Coalesced float4 reads along k; coalesced chunk writes.
// ---------------------------------------------------------------------------
__global__ __launch_bounds__(256)
void esplit(const float* __restrict__ src, _Float16* __restrict__ dst) {
    __shared__ _Float16 tile[32][132];
    const int rt = blockIdx.x, kc = blockIdx.y;   // KT = 32
    const int kli = threadIdx.x & 31;          // k-granule (float4)
    const int rl  = threadIdx.x >> 5;          // 0..7
    #pragma unroll
    for (int rr = 0; rr < 4; ++rr) {
        const int row = rl * 4 + rr;
        const float4 v = *(const float4*)&src[(size_t)(rt * 32 + row) * 512 + kc * 128 + kli * 4];
        tile[row][kli * 4 + 0] = (_Float16)v.x;
        tile[row][kli * 4 + 1] = (_Float16)v.y;
        tile[row][kli * 4 + 2] = (_Float16)v.z;
        tile[row][kli * 4 + 3] = (_Float16)v.w;
    }
    __syncthreads();

    #pragma unroll
    for (int p = 0; p < 2; ++p) {
        const int slot = p * 256 + threadIdx.x;
        const int ktl  = slot >> 6, l = slot & 63;
        f16x8 v;
        #pragma unroll
        for (int j = 0; j < 8; ++j)
            v[j] = tile[l & 31][ktl * 16 + ((l >> 5) << 3) + j];
        const int kt = kc * 8 + ktl;
        *(f16x8*)&dst[((size_t)rt * 32 + kt) * 512 + l * 8] = v;
    }
}

// ---------------------------------------------------------------------------
// Final FC on time-averaged h: out[b,c] = hbar[b,:] . fc_w[:,c] + fc_b[c]
// ---------------------------------------------------------------------------
__global__ __launch_bounds__(64)
void final_fc(const float* __restrict__ hbar, const float* __restrict__ fcw,
              const float* __restrict__ fcb, float* __restrict__ out) {
    __shared__ float hrow[HIDN];
    const int b = blockIdx.x;
    for (int i = threadIdx.x; i < HIDN; i += 64)
        hrow[i] = hbar[(size_t)b * HIDN + i];
    __syncthreads();

    const int c = threadIdx.x;
    if (c < NCLASS) {
        float acc = fcb[c];
        #pragma unroll 8
        for (int k = 0; k < HIDN; ++k)
            acc = fmaf(hrow[k], fcw[(size_t)k * NCLASS + c], acc);
        out[(size_t)b * NCLASS + c] = acc;
    }
}

// ---------------------------------------------------------------------------
extern "C" void kernel_launch(void* const* d_in, const int* in_sizes, int n_in,
                              void* d_out, int out_size, void* d_ws, size_t ws_size,
                              hipStream_t stream) {
    const float* x   = (const float*)d_in[0];
    const float* W0  = (const float*)d_in[1];
    const float* W1  = (const float*)d_in[2];
    const float* W2  = (const float*)d_in[3];
    const float* vc0 = (const float*)d_in[4];
    const float* vc1 = (const float*)d_in[5];
    const float* vc2 = (const float*)d_in[6];
    const float* b0  = (const float*)d_in[7];
    const float* b1  = (const float*)d_in[8];
    const float* b2  = (const float*)d_in[9];
    const float* fcw = (const float*)d_in[10];
    const float* fcb = (const float*)d_in[11];
    float* out = (float*)d_out;

    char* ws = (char*)d_ws;
    size_t off = 0;
    auto carve = [&](size_t bytes) { char* p = ws + off; off = (off + bytes + 255) & ~255ull; return p; };

    _Float16* W0t = (_Float16*)carve((size_t)4096 * 512 * 2);
    _Float16* W1t = (_Float16*)carve((size_t)3072 * 1024 * 2);
    _Float16* W2t = (_Float16*)carve((size_t)3072 * 1024 * 2);
    const size_t W_BYTES = off;

    const size_t PER_B = 12ull * 512 * 2 + 2ull * 12 * 1024 * 2 + 1024ull * 4 + 1024;
    int CB = 32;
    if      (W_BYTES + 2048ull * PER_B <= ws_size) CB = 2048;
    else if (W_BYTES + 1024ull * PER_B <= ws_size) CB = 1024;
    else if (W_BYTES +  512ull * PER_B <= ws_size) CB = 512;
    else if (W_BYTES +  256ull * PER_B <= ws_size) CB = 256;
    else if (W_BYTES +  128ull * PER_B <= ws_size) CB = 128;
    else if (W_BYTES +   64ull * PER_B <= ws_size) CB = 64;
    const int MC = CB * TSTEPS;

    _Float16* x16  = (_Float16*)carve((size_t)MC * 512 * 2);
    _Float16* hA16 = (_Float16*)carve((size_t)MC * 1024 * 2);
    _Float16* hB16 = (_Float16*)carve((size_t)MC * 1024 * 2);
    float*    hbar = (float*)carve((size_t)CB * 1024 * 4);

    const dim3 blk256(256);

    // weight prep: grid (plane-rows/32, K/128)
    wsplit_t<4><<<dim3(4096 / 32, 512 / 128),  blk256, 0, stream>>>(W0, W0t, 512);
    wsplit_t<3><<<dim3(3072 / 32, 1024 / 128), blk256, 0, stream>>>(W1, W1t, 1024);
    wsplit_t<3><<<dim3(3072 / 32, 1024 / 128), blk256, 0, stream>>>(W2, W2t, 1024);

    for (int cb = 0; cb < BATCH / CB; ++cb) {
        const float* xc   = x   + (size_t)cb * CB * TSTEPS * IMG;
        float*       outc = out + (size_t)cb * CB * NCLASS;

        // layer 0: x -> fragment fp16; fused GEMM(K=512, BN=128, NCOMP=4)
        esplit<<<dim3(MC / 32, 4), blk256, 0, stream>>>(xc, x16);
        gemm_sru<2, 4><<<dim3(4096 / 128, MC / 192), blk256, 0, stream>>>(
            x16, W0t, nullptr, vc0, b0, hA16, nullptr, 512, 2);   // pc=4

        // layer 1: fused GEMM(K=1024, BN=192, NCOMP=3)
        gemm_sru<3, 3><<<dim3(3072 / 192, MC / 192), blk256, 0, stream>>>(
            hA16, W1t, hA16, vc1, b1, hB16, nullptr, 1024, 1);    // pc=2

        // layer 2: fused; emit hbar only
        gemm_sru<3, 3><<<dim3(3072 / 192, MC / 192), blk256, 0, stream>>>(
            hB16, W2t, hB16, vc2, b2, nullptr, hbar, 1024, 1);

        final_fc<<<dim3(CB), dim3(64), 0, stream>>>(hbar, fcw, fcb, outc);
    }
}

// Round 10
// 748.095 us; speedup vs baseline: 1.0377x; 1.0377x over previous
//
#include <hip/hip_runtime.h>
#include <math.h>

#define TSTEPS 12
#define BATCH  2048
#define IMG    512
#define HIDN   1024
#define NCLASS 51
#define SCALE_X 1.7320508075688772f      // sqrt(1 + 2*e^0) = sqrt(3)

typedef __attribute__((ext_vector_type(8)))  _Float16 f16x8;
typedef __attribute__((ext_vector_type(2)))  _Float16 f16x2;
typedef __attribute__((ext_vector_type(16))) float    f32x16;

__device__ __forceinline__ float sigf(float x) {
    return 1.f / (1.f + __expf(-x));
}

// s_waitcnt imm: vmcnt(n) in [3:0], lgkmcnt=15 (no wait), expcnt=7 (no wait)
#define VMCNT_IMM(n) (0x0F70 | (n))

// ===========================================================================
// Fragment-ordered layout (as R8/R9): matrix [R x K] fp16 stored as 1KB
// chunks over (rt=row/32, kt=k/16); chunk idx = rt*(K/16)+kt; lane l owns
// halfs [l*8,l*8+8) = (row = rt*32+(l&31), k = kt*16+(l>>5)*8+j). Matches
// the v_mfma_f32_32x32x16_f16 A/B fragment.
// ===========================================================================

// ---------------------------------------------------------------------------
// Fused fp16 MFMA GEMM + SRU recurrence. 32x32x16 MFMA.
// A: LDS 4-buffer ring via global_load_lds (manual vmcnt + raw s_barrier).
// B: NEVER in LDS -- per-wave register fragments loaded directly from the
// XCD-L2-resident weight plane (1KB coalesced loads), double-buffered one
// iter ahead; compiler inserts fine-grained vmcnt per use (AITER pattern).
// LDS traffic per block-iter: 24KB read + 12KB DMA-write (was 72KB).
// Requires K % 128 == 0 (512, 1024 here).
// ---------------------------------------------------------------------------
template<int TJ, int NCOMP>
__global__ __launch_bounds__(256, 2)
void gemm_sru(const _Float16* __restrict__ A, const _Float16* __restrict__ Bt,
              const _Float16* __restrict__ resid,
              const float* __restrict__ vc, const float* __restrict__ bias,
              _Float16* __restrict__ hout, float* __restrict__ hbar, int K,
              int pcshift) {
    constexpr int BN    = 64 * TJ;
    constexpr int NCH   = BN / NCOMP;
    constexpr int ATILE = 192 * 32;            // halfs per A buffer (12 KB)
    constexpr int EPAD  = BN + 8;
    constexpr int EPI   = 96 * EPAD;
    constexpr int HREG  = 96 * NCH;
    constexpr int KTH   = NCH / 16;
    constexpr int PAIRS = NCH / 2;
    constexpr int STG   = 4 * ATILE;           // 4-buffer ring (48 KB)
    constexpr int TOT   = STG > (EPI + HREG) ? STG : (EPI + HREG);
    __shared__ __align__(16) _Float16 smem[TOT];

    const int tid  = threadIdx.x;
    const int lane = tid & 63;
    const int w    = tid >> 6;

    // ---- XCD swizzle: columns ≡ xk (mod 8) stay on one XCD (W-stationary) --
    const int nbx = gridDim.x;
    const int b   = blockIdx.y * nbx + blockIdx.x;
    const int pc1 = (nbx >> 3) - 1;
    const int xk  = b & 7, s = b >> 3;
    const int bx  = xk + ((s & pc1) << 3);
    const int by  = s >> pcshift;

    const int bm  = by * 192;
    const int KT  = K >> 4;

    // ---- A staging: each wave stages 3 of the 12 chunk-loads per k-step ----
    const int rt0 = bm >> 5;
    auto stageA = [&](int buf, int k0) {
        const int kt0 = k0 >> 4;
        #pragma unroll
        for (int i = 0; i < 3; ++i) {
            const int L = w * 3 + i, rc = L >> 1, kk = L & 1;
            const _Float16* g = A + ((size_t)(rt0 + rc) * KT + kt0 + kk) * 512 + (lane << 3);
            __builtin_amdgcn_global_load_lds(
                (const __attribute__((address_space(1))) unsigned int*)g,
                (__attribute__((address_space(3))) unsigned int*)(smem + buf * ATILE + L * 512),
                16, 0, 0);
        }
    };

    const int wy32 = (w >> 1) * 3;             // wave row-chunk origin
    const int wx32 = (w & 1) * TJ;             // wave col-chunk origin
    const int l5   = lane >> 5;
    const int m32  = lane & 31;

    // B fragment base: chunk (bx*(BN/32) + wx32 + j, kt)
    const _Float16* bglob = Bt + (size_t)(bx * (BN >> 5) + wx32) * KT * 512 + (lane << 3);

    f16x8 bfr[2][2][TJ];                       // [slot][ks][j]
    auto loadB = [&](int k0, int slot) {
        const int kt0 = k0 >> 4;
        #pragma unroll
        for (int ks = 0; ks < 2; ++ks)
            #pragma unroll
            for (int j = 0; j < TJ; ++j)
                bfr[slot][ks][j] = *(const f16x8*)&bglob[((size_t)j * KT + kt0 + ks) * 512];
    };

    f32x16 acc[3][TJ];
    #pragma unroll
    for (int i = 0; i < 3; ++i)
        #pragma unroll
        for (int j = 0; j < TJ; ++j)
            #pragma unroll
            for (int r = 0; r < 16; ++r) acc[i][j][r] = 0.f;

    stageA(0, 0);
    stageA(1, 32);
    loadB(0, 0);

    for (int K0 = 0; K0 < K; K0 += 128) {
        #pragma unroll
        for (int u = 0; u < 4; ++u) {
            const int k0 = K0 + u * 32;
            // wait own stage A(i); allowed in flight: A(i+1)=3 + B(i)=2TJ
            if (k0 + 32 < K) __builtin_amdgcn_s_waitcnt(VMCNT_IMM(3 + 2 * TJ));
            else             __builtin_amdgcn_s_waitcnt(VMCNT_IMM(2 * TJ));
            __builtin_amdgcn_s_barrier();
            if (k0 + 64 < K) stageA((u + 2) & 3, k0 + 64);
            if (k0 + 32 < K) loadB(k0 + 32, (u + 1) & 1);

            const _Float16* la = smem + u * ATILE;
            #pragma unroll
            for (int ks = 0; ks < 2; ++ks) {
                f16x8 a[3];
                #pragma unroll
                for (int i = 0; i < 3; ++i)
                    a[i] = *(const f16x8*)&la[((wy32 + i) * 2 + ks) * 512 + (lane << 3)];
                #pragma unroll
                for (int i = 0; i < 3; ++i)
                    #pragma unroll
                    for (int j = 0; j < TJ; ++j)
                        acc[i][j] = __builtin_amdgcn_mfma_f32_32x32x16_f16(
                            a[i], bfr[u & 1][ks][j], acc[i][j], 0, 0, 0);
            }
        }
    }

    // ---- epilogue: two passes of 96 rows (8 whole batches each) ------------
    _Float16 (*uld)[EPAD] = (_Float16 (*)[EPAD])smem;
    _Float16* hreg = smem + EPI;
    const int bl   = tid / PAIRS;
    const int pr   = tid % PAIRS;
    const int gcol = bx * NCH + pr * 2;

    #pragma unroll
    for (int pass = 0; pass < 2; ++pass) {
        __syncthreads();
        if ((w >> 1) == pass) {
            #pragma unroll
            for (int i = 0; i < 3; ++i)
                #pragma unroll
                for (int j = 0; j < TJ; ++j)
                    #pragma unroll
                    for (int r = 0; r < 16; ++r) {
                        const int row = i * 32 + (r & 3) + 8 * (r >> 2) + 4 * l5;
                        uld[row][(wx32 + j) * 32 + m32] = (_Float16)acc[i][j][r];
                    }
        }
        __syncthreads();

        if (tid < 8 * PAIRS) {
            const float2 vf  = *(const float2*)&vc[gcol];
            const float2 vr  = *(const float2*)&vc[HIDN + gcol];
            const float2 bfv = *(const float2*)&bias[gcol];
            const float2 brv = *(const float2*)&bias[HIDN + gcol];
            const int ca = (pr * 2) * NCOMP, cb = (pr * 2 + 1) * NCOMP;

            float c0 = 0.f, c1 = 0.f, s0 = 0.f, s1 = 0.f;
            #pragma unroll
            for (int t = 0; t < TSTEPS; ++t) {
                const int row = bl * 12 + t;
                const float u0a = (float)uld[row][ca + 0];
                const float u1a = (float)uld[row][ca + 1];
                const float u2a = (float)uld[row][ca + 2];
                const float u0b = (float)uld[row][cb + 0];
                const float u1b = (float)uld[row][cb + 1];
                const float u2b = (float)uld[row][cb + 2];
                float xta, xtb;
                if (NCOMP == 4) {
                    xta = (float)uld[row][ca + 3];
                    xtb = (float)uld[row][cb + 3];
                } else {
                    const int grow = bm + pass * 96 + row;
                    const size_t gran = ((size_t)(grow >> 5) * KT + (gcol >> 4)) * 512
                                      + (size_t)((grow & 31) + ((gcol >> 3) & 1) * 32) * 8
                                      + (gcol & 7);
                    const f16x2 xv = *(const f16x2*)&resid[gran];
                    xta = (float)xv[0]; xtb = (float)xv[1];
                }

                const float f0 = sigf(u1a + vf.x * c0 + bfv.x);
                c0 = f0 * c0 + (1.f - f0) * u0a;
                const float r0_ = sigf(u2a + vr.x * c0 + brv.x);
                const float th0 = 2.f * sigf(2.f * c0) - 1.f;
                const float hv0 = r0_ * th0 + (1.f - r0_) * xta * SCALE_X;

                const float f1 = sigf(u1b + vf.y * c1 + bfv.y);
                c1 = f1 * c1 + (1.f - f1) * u0b;
                const float r1_ = sigf(u2b + vr.y * c1 + brv.y);
                const float th1 = 2.f * sigf(2.f * c1) - 1.f;
                const float hv1 = r1_ * th1 + (1.f - r1_) * xtb * SCALE_X;

                if (hout) {
                    const int rtl  = row >> 5;
                    const int ktl  = pr >> 3;
                    const int lloc = (row & 31) + ((pr >> 2) & 1) * 32;
                    f16x2 hv = { (_Float16)hv0, (_Float16)hv1 };
                    *(f16x2*)&hreg[(rtl * KTH + ktl) * 512 + lloc * 8 + (pr & 3) * 2] = hv;
                }
                s0 += hv0; s1 += hv1;
            }
            if (hbar) {
                const int gb = bm / 12 + pass * 8 + bl;
                *(float2*)&hbar[(size_t)gb * HIDN + gcol] =
                    make_float2(s0 * (1.f / TSTEPS), s1 * (1.f / TSTEPS));
            }
        }

        if (hout) {
            __syncthreads();
            const int rtg0 = (bm + pass * 96) >> 5;
            for (int g = tid; g < HREG / 8; g += 256) {
                const int c = g >> 6, l = g & 63;
                const f16x8 v = *(const f16x8*)&hreg[c * 512 + l * 8];
                const int rtl = c / KTH, ktl = c % KTH;
                const size_t gc = (size_t)(rtg0 + rtl) * 64 + bx * KTH + ktl;
                *(f16x8*)&hout[gc * 512 + l * 8] = v;
            }
        }
    }
}

// ---------------------------------------------------------------------------
// Weight prep (coalesced, LDS transpose): W (K x N fp32, col n = comp*1024+h)
// -> fragment-ordered fp16 plane, row n' = h*NC + comp.
// ---------------------------------------------------------------------------
template<int NC>
__global__ __launch_bounds__(256)
void wsplit_t(const float* __restrict__ W, _Float16* __restrict__ Wt, int K) {
    __shared__ _Float16 tile[32][132];
    const int N  = NC * 1024;
    const int KT = K >> 4;
    const int rt = blockIdx.x, kc = blockIdx.y;

    const int nl = threadIdx.x & 31;
    const int kl = threadIdx.x >> 5;
    const int np = rt * 32 + nl;
    const int h  = np / NC, comp = np - h * NC;
    const int n  = comp * 1024 + h;
    #pragma unroll
    for (int kk = 0; kk < 16; ++kk) {
        const int k = kc * 128 + kl * 16 + kk;
        tile[nl][kl * 16 + kk] = (_Float16)W[(size_t)k * N + n];
    }
    __syncthreads();

    #pragma unroll
    for (int p = 0; p < 2; ++p) {
        const int slot = p * 256 + threadIdx.x;
        const int ktl  = slot >> 6, l = slot & 63;
        f16x8 v;
        #pragma unroll
        for (int j = 0; j < 8; ++j)
            v[j] = tile[l & 31][ktl * 16 + ((l >> 5) << 3) + j];
        const int kt = kc * 8 + ktl;
        *(f16x8*)&Wt[((size_t)rt * KT + kt) * 512 + l * 8] = v;
    }
}

// ---------------------------------------------------------------------------
// x (rows x 512 fp32 row-major) -> fragment-ordered fp16.
// ---------------------------------------------------------------------------
__global__ __launch_bounds__(256)
void esplit(const float* __restrict__ src, _Float16* __restrict__ dst) {
    __shared__ _Float16 tile[32][132];
    const int rt = blockIdx.x, kc = blockIdx.y;
    const int kli = threadIdx.x & 31;
    const int rl  = threadIdx.x >> 5;
    #pragma unroll
    for (int rr = 0; rr < 4; ++rr) {
        const int row = rl * 4 + rr;
        const float4 v = *(const float4*)&src[(size_t)(rt * 32 + row) * 512 + kc * 128 + kli * 4];
        tile[row][kli * 4 + 0] = (_Float16)v.x;
        tile[row][kli * 4 + 1] = (_Float16)v.y;
        tile[row][kli * 4 + 2] = (_Float16)v.z;
        tile[row][kli * 4 + 3] = (_Float16)v.w;
    }
    __syncthreads();

    #pragma unroll
    for (int p = 0; p < 2; ++p) {
        const int slot = p * 256 + threadIdx.x;
        const int ktl  = slot >> 6, l = slot & 63;
        f16x8 v;
        #pragma unroll
        for (int j = 0; j < 8; ++j)
            v[j] = tile[l & 31][ktl * 16 + ((l >> 5) << 3) + j];
        const int kt = kc * 8 + ktl;
        *(f16x8*)&dst[((size_t)rt * 32 + kt) * 512 + l * 8] = v;
    }
}

// ---------------------------------------------------------------------------
// Final FC on time-averaged h: out[b,c] = hbar[b,:] . fc_w[:,c] + fc_b[c]
// ---------------------------------------------------------------------------
__global__ __launch_bounds__(64)
void final_fc(const float* __restrict__ hbar, const float* __restrict__ fcw,
              const float* __restrict__ fcb, float* __restrict__ out) {
    __shared__ float hrow[HIDN];
    const int b = blockIdx.x;
    for (int i = threadIdx.x; i < HIDN; i += 64)
        hrow[i] = hbar[(size_t)b * HIDN + i];
    __syncthreads();

    const int c = threadIdx.x;
    if (c < NCLASS) {
        float acc = fcb[c];
        #pragma unroll 8
        for (int k = 0; k < HIDN; ++k)
            acc = fmaf(hrow[k], fcw[(size_t)k * NCLASS + c], acc);
        out[(size_t)b * NCLASS + c] = acc;
    }
}

// ---------------------------------------------------------------------------
extern "C" void kernel_launch(void* const* d_in, const int* in_sizes, int n_in,
                              void* d_out, int out_size, void* d_ws, size_t ws_size,
                              hipStream_t stream) {
    const float* x   = (const float*)d_in[0];
    const float* W0  = (const float*)d_in[1];
    const float* W1  = (const float*)d_in[2];
    const float* W2  = (const float*)d_in[3];
    const float* vc0 = (const float*)d_in[4];
    const float* vc1 = (const float*)d_in[5];
    const float* vc2 = (const float*)d_in[6];
    const float* b0  = (const float*)d_in[7];
    const float* b1  = (const float*)d_in[8];
    const float* b2  = (const float*)d_in[9];
    const float* fcw = (const float*)d_in[10];
    const float* fcb = (const float*)d_in[11];
    float* out = (float*)d_out;

    char* ws = (char*)d_ws;
    size_t off = 0;
    auto carve = [&](size_t bytes) { char* p = ws + off; off = (off + bytes + 255) & ~255ull; return p; };

    _Float16* W0t = (_Float16*)carve((size_t)4096 * 512 * 2);
    _Float16* W1t = (_Float16*)carve((size_t)3072 * 1024 * 2);
    _Float16* W2t = (_Float16*)carve((size_t)3072 * 1024 * 2);
    const size_t W_BYTES = off;

    const size_t PER_B = 12ull * 512 * 2 + 2ull * 12 * 1024 * 2 + 1024ull * 4 + 1024;
    int CB = 32;
    if      (W_BYTES + 2048ull * PER_B <= ws_size) CB = 2048;
    else if (W_BYTES + 1024ull * PER_B <= ws_size) CB = 1024;
    else if (W_BYTES +  512ull * PER_B <= ws_size) CB = 512;
    else if (W_BYTES +  256ull * PER_B <= ws_size) CB = 256;
    else if (W_BYTES +  128ull * PER_B <= ws_size) CB = 128;
    else if (W_BYTES +   64ull * PER_B <= ws_size) CB = 64;
    const int MC = CB * TSTEPS;

    _Float16* x16  = (_Float16*)carve((size_t)MC * 512 * 2);
    _Float16* hA16 = (_Float16*)carve((size_t)MC * 1024 * 2);
    _Float16* hB16 = (_Float16*)carve((size_t)MC * 1024 * 2);
    float*    hbar = (float*)carve((size_t)CB * 1024 * 4);

    const dim3 blk256(256);

    wsplit_t<4><<<dim3(4096 / 32, 512 / 128),  blk256, 0, stream>>>(W0, W0t, 512);
    wsplit_t<3><<<dim3(3072 / 32, 1024 / 128), blk256, 0, stream>>>(W1, W1t, 1024);
    wsplit_t<3><<<dim3(3072 / 32, 1024 / 128), blk256, 0, stream>>>(W2, W2t, 1024);

    for (int cb = 0; cb < BATCH / CB; ++cb) {
        const float* xc   = x   + (size_t)cb * CB * TSTEPS * IMG;
        float*       outc = out + (size_t)cb * CB * NCLASS;

        // layer 0: x -> fragment fp16; fused GEMM(K=512, BN=128, NCOMP=4)
        esplit<<<dim3(MC / 32, 4), blk256, 0, stream>>>(xc, x16);
        gemm_sru<2, 4><<<dim3(4096 / 128, MC / 192), blk256, 0, stream>>>(
            x16, W0t, nullptr, vc0, b0, hA16, nullptr, 512, 2);   // pc=4

        // layer 1: fused GEMM(K=1024, BN=192, NCOMP=3)
        gemm_sru<3, 3><<<dim3(3072 / 192, MC / 192), blk256, 0, stream>>>(
            hA16, W1t, hA16, vc1, b1, hB16, nullptr, 1024, 1);    // pc=2

        // layer 2: fused; emit hbar only
        gemm_sru<3, 3><<<dim3(3072 / 192, MC / 192), blk256, 0, stream>>>(
            hB16, W2t, hB16, vc2, b2, nullptr, hbar, 1024, 1);

        final_fc<<<dim3(CB), dim3(64), 0, stream>>>(hbar, fcw, fcb, outc);
    }
}